// Round 4
// baseline (275.487 us; speedup 1.0000x reference)
//
#include <hip/hip_runtime.h>

// Problem constants (B,S,D_IN,D_HID,D_OUT) = (8,4096,512,1024,512)
#define B_    8
#define S_    4096
#define DIN   512
#define DHID  1024
#define DOUT  512
#define M_    (B_*S_)          // 32768
#define NCAT  (DHID + DOUT)    // 1536
#define CH2   32
#define NCH2  (S_/CH2)         // 128

typedef __bf16 bf16x8 __attribute__((ext_vector_type(8)));
typedef float  floatx4 __attribute__((ext_vector_type(4)));

__device__ __forceinline__ unsigned short f2bf(float f) {
  unsigned u = __builtin_bit_cast(unsigned, f);
  u = (u + 0x7FFFu + ((u >> 16) & 1u)) >> 16;   // RNE
  return (unsigned short)u;
}
__device__ __forceinline__ float bf2f(unsigned short h) {
  unsigned u = ((unsigned)h) << 16;
  return __builtin_bit_cast(float, u);
}

__device__ __forceinline__ void gl_lds16(const unsigned short* g, unsigned short* l) {
  __builtin_amdgcn_global_load_lds((const __attribute__((address_space(1))) void*)g,
                                   (__attribute__((address_space(3))) void*)l, 16, 0, 0);
}

// ---------- fused prep: wcat | woutt | a_s | x->bf16 (single launch) ----------
__global__ void prep_all(const float* __restrict__ logit,
                         const float* __restrict__ Win, const float* __restrict__ Wdx,
                         const float* __restrict__ Wout, const float* __restrict__ x,
                         float* __restrict__ a_s,
                         unsigned short* __restrict__ wcat,
                         unsigned short* __restrict__ woutt,
                         unsigned short* __restrict__ xb) {
  int bx = blockIdx.x;
  if (bx < 3072) {                       // Wcat^T: n in [0,1536), k in [0,512)
    int idx = bx * 256 + threadIdx.x;
    int n = idx >> 9, k = idx & 511;
    float v = (n < DHID) ? Win[(size_t)k * DHID + n] : Wdx[(size_t)k * DOUT + (n - DHID)];
    wcat[idx] = f2bf(v);
  } else if (bx < 5120) {                // Wout^T: n in [0,512), k in [0,1024)
    int idx = (bx - 3072) * 256 + threadIdx.x;
    int n = idx >> 10, k = idx & 1023;
    woutt[idx] = f2bf(Wout[(size_t)k * DOUT + n]);
  } else if (bx < 5124) {                // a_s
    int d = (bx - 5120) * 256 + threadIdx.x;
    if (d < DHID) {
      float a = 1.f / (1.f + expf(-logit[d]));
      a_s[d] = a;
      a_s[DHID + d] = sqrtf(fmaxf(1.f - a * a, 0.f));
    }
  } else {                               // x fp32 -> bf16, 8 elems/thread
    size_t i = (size_t)(bx - 5124) * 256 + threadIdx.x;
    const float4* p = (const float4*)x;
    float4 v0 = p[i * 2];
    float4 v1 = p[i * 2 + 1];
    uint4 o;
    o.x = (unsigned)f2bf(v0.x) | ((unsigned)f2bf(v0.y) << 16);
    o.y = (unsigned)f2bf(v0.z) | ((unsigned)f2bf(v0.w) << 16);
    o.z = (unsigned)f2bf(v1.x) | ((unsigned)f2bf(v1.y) << 16);
    o.w = (unsigned)f2bf(v1.z) | ((unsigned)f2bf(v1.w) << 16);
    *(uint4*)&xb[i * 8] = o;
  }
}

// ================= COARSE 256x256 GEMM (r3-proven; used for GEMM1, K=512) ==========
// Granule = 32-K slab, 4 LDS slots, prefetch distance 3, per granule:
// stage(t+3) -> 12 ds_read_b128 -> 32 MFMA -> vmcnt(8)+lgkmcnt(0) -> barrier.
template <int K, int MODE, int NTN>
__global__ __launch_bounds__(512, 2) void gemm256c(
    const unsigned short* __restrict__ A,
    const unsigned short* __restrict__ Bt,
    const float* __restrict__ a_s,
    const float* __restrict__ bias0,
    const float* __restrict__ bias1,
    unsigned short* __restrict__ u_out,
    unsigned short* __restrict__ dx_buf,
    const unsigned short* __restrict__ dx_in,
    float* __restrict__ out,
    float* __restrict__ carry)
{
  constexpr int NG = K / 32;             // granules
  __shared__ __align__(16) unsigned char smem[131072];
  unsigned char* lds = smem;

  const int tid  = threadIdx.x;
  const int lane = tid & 63, wid = tid >> 6;
  const int r16  = lane & 15, quad = lane >> 4;
  const int wm = (wid >> 2) * 128, wn = (wid & 3) * 64;
  const int csw = (quad ^ ((r16 >> 1) & 3)) << 4;   // read-side swizzled 16B chunk

  constexpr int TOT = (M_ / 256) * NTN;
  const int flat = blockIdx.x;
  const int jj = (flat & 7) * (TOT / 8) + (flat >> 3);
  const int nt = jj % NTN, mt = jj / NTN;
  const int n0 = nt * 256, m0 = mt * 256;

  const int srow = (wid << 4) + (lane >> 2);                 // 0..127
  const int scol = ((lane & 3) ^ ((lane >> 3) & 3)) << 3;    // pre-swizzled src chunk
  const unsigned short* gA0 = A  + (size_t)(m0 + srow) * K + scol;
  const unsigned short* gB0 = Bt + (size_t)(n0 + srow) * K + scol;
  const unsigned oA = (unsigned)wid * 1024u + (unsigned)lane * 16u;  // linear LDS bytes

  floatx4 acc[8][4] = {};

  auto stage = [&](int slot, int g) {
    unsigned char* d = lds + slot * 32768;
    const unsigned short* sa = gA0 + (size_t)g * 32;
    const unsigned short* sb = gB0 + (size_t)g * 32;
    gl_lds16(sa, (unsigned short*)(d + oA));
    gl_lds16(sa + (size_t)128 * K, (unsigned short*)(d + oA + 8192));
    gl_lds16(sb, (unsigned short*)(d + 16384 + oA));
    gl_lds16(sb + (size_t)128 * K, (unsigned short*)(d + 16384 + oA + 8192));
  };

  auto compute = [&](int slot) {
    const unsigned char* pA = lds + slot * 32768;
    const unsigned char* pB = pA + 16384;
    bf16x8 af[8], bfr[4];
#pragma unroll
    for (int j = 0; j < 4; ++j)
      bfr[j] = *(const bf16x8*)(pB + (wn + j * 16 + r16) * 64 + csw);
#pragma unroll
    for (int i = 0; i < 8; ++i)
      af[i] = *(const bf16x8*)(pA + (wm + i * 16 + r16) * 64 + csw);
    __builtin_amdgcn_s_setprio(1);
#pragma unroll
    for (int i = 0; i < 8; ++i)
#pragma unroll
      for (int j = 0; j < 4; ++j)
        acc[i][j] = __builtin_amdgcn_mfma_f32_16x16x32_bf16(af[i], bfr[j], acc[i][j], 0, 0, 0);
    __builtin_amdgcn_s_setprio(0);
  };

  stage(0, 0); stage(1, 1); stage(2, 2);
  asm volatile("s_waitcnt vmcnt(8)" ::: "memory");
  __builtin_amdgcn_s_barrier();

  for (int t = 0; t < NG - 3; ++t) {
    stage((t + 3) & 3, t + 3);
    compute(t & 3);
    asm volatile("s_waitcnt vmcnt(8) lgkmcnt(0)" ::: "memory");
    __builtin_amdgcn_s_barrier();
  }
  compute((NG - 3) & 3);
  asm volatile("s_waitcnt vmcnt(4) lgkmcnt(0)" ::: "memory");
  __builtin_amdgcn_s_barrier();
  compute((NG - 2) & 3);
  asm volatile("s_waitcnt vmcnt(0) lgkmcnt(0)" ::: "memory");
  __builtin_amdgcn_s_barrier();
  compute((NG - 1) & 3);
  asm volatile("s_waitcnt lgkmcnt(0)" ::: "memory");
  __builtin_amdgcn_s_barrier();

  // ---- epilogue (conflict-free): 4 passes of 64 rows, fp32 stride 260 ----
  float* stg = (float*)smem;
  const bool isU = (MODE == 0) && (n0 < DHID);
  const int c4 = lane << 2;

  float4 bv = {}, sv = {};
  if (MODE == 0) {
    if (isU) { bv = *(const float4*)&bias0[n0 + c4]; sv = *(const float4*)&a_s[DHID + n0 + c4]; }
    else     { bv = *(const float4*)&bias1[(n0 - DHID) + c4]; }
  } else {
    bv = *(const float4*)&bias0[n0 + c4];
  }

  const int colS = tid & 255, ch = tid >> 8;
  float aa = 0.f, sbi = 0.f, ssc = 0.f;
  if (isU) { aa = a_s[n0 + colS]; sbi = bias0[n0 + colS]; ssc = a_s[DHID + n0 + colS]; }

#pragma unroll
  for (int p = 0; p < 4; ++p) {
    if ((wid >> 2) == (p >> 1)) {
      const int ib = (p & 1) * 4;
#pragma unroll
      for (int ii = 0; ii < 4; ++ii)
#pragma unroll
        for (int j = 0; j < 4; ++j) {
          const int col = (wid & 3) * 64 + j * 16 + r16;
#pragma unroll
          for (int r = 0; r < 4; ++r)
            stg[(ii * 16 + quad * 4 + r) * 260 + col] = acc[ib + ii][j][r];
        }
    }
    asm volatile("s_waitcnt lgkmcnt(0)" ::: "memory");
    __builtin_amdgcn_s_barrier();

    const int gmb = m0 + p * 64;
    if (isU) {
      float P = 0.f;
      const float* sp = &stg[(ch * 32) * 260 + colS];
#pragma unroll
      for (int r = 0; r < 32; ++r) { P = fmaf(aa, P, (sp[0] + sbi) * ssc); sp += 260; }
      const int gm0 = gmb + ch * 32;
      carry[((size_t)(gm0 >> 12) * NCH2 + ((gm0 & 4095) >> 5)) * DHID + n0 + colS] = P;
#pragma unroll
      for (int rr = 0; rr < 8; ++rr) {
        const int lr = (wid << 3) + rr;
        float4 v = *(const float4*)&stg[lr * 260 + c4];
        ushort4 o;
        o.x = f2bf((v.x + bv.x) * sv.x);
        o.y = f2bf((v.y + bv.y) * sv.y);
        o.z = f2bf((v.z + bv.z) * sv.z);
        o.w = f2bf((v.w + bv.w) * sv.w);
        *(ushort4*)&u_out[(size_t)(gmb + lr) * DHID + n0 + c4] = o;
      }
    } else if (MODE == 0) {
#pragma unroll
      for (int rr = 0; rr < 8; ++rr) {
        const int lr = (wid << 3) + rr;
        float4 v = *(const float4*)&stg[lr * 260 + c4];
        ushort4 o;
        o.x = f2bf(v.x + bv.x);
        o.y = f2bf(v.y + bv.y);
        o.z = f2bf(v.z + bv.z);
        o.w = f2bf(v.w + bv.w);
        *(ushort4*)&dx_buf[(size_t)(gmb + lr) * DOUT + (n0 - DHID) + c4] = o;
      }
    } else {
#pragma unroll
      for (int rr = 0; rr < 8; ++rr) {
        const int lr = (wid << 3) + rr;
        float4 v = *(const float4*)&stg[lr * 260 + c4];
        ushort4 dv = *(const ushort4*)&dx_in[(size_t)(gmb + lr) * DOUT + n0 + c4];
        float4 o;
        o.x = (v.x + bv.x + bf2f(dv.x)) * 0.5f;
        o.y = (v.y + bv.y + bf2f(dv.y)) * 0.5f;
        o.z = (v.z + bv.z + bf2f(dv.z)) * 0.5f;
        o.w = (v.w + bv.w + bf2f(dv.w)) * 0.5f;
        *(float4*)&out[(size_t)(gmb + lr) * DOUT + n0 + c4] = o;
      }
    }
    __builtin_amdgcn_s_barrier();
  }
}

// ================= FINE-PHASED 256x256 GEMM (r2-proven; used for GEMM2, K=1024) ====
// Per granule 2 phases (i-halves, 16 MFMA each): {ds_read ; 2x global_load_lds ;
// s_barrier ; lgkmcnt(0) ; setprio(1) MFMA setprio(0) ; s_barrier}; vmcnt(8) once
// per granule. Measured (r2 vs r3 subtraction): ~28 us faster than coarse at K=1024.
template <int K, int MODE, int NTN>
__global__ __launch_bounds__(512, 2) void gemm256f(
    const unsigned short* __restrict__ A,
    const unsigned short* __restrict__ Bt,
    const float* __restrict__ a_s,
    const float* __restrict__ bias0,
    const float* __restrict__ bias1,
    unsigned short* __restrict__ u_out,
    unsigned short* __restrict__ dx_buf,
    const unsigned short* __restrict__ dx_in,
    float* __restrict__ out,
    float* __restrict__ carry)
{
  constexpr int NG = K / 32;             // granules
  __shared__ __align__(16) unsigned char smem[131072];
  unsigned char* lds = smem;

  const int tid  = threadIdx.x;
  const int lane = tid & 63, wid = tid >> 6;
  const int r16  = lane & 15, quad = lane >> 4;
  const int wm = (wid >> 2) * 128, wn = (wid & 3) * 64;
  const int csw = (quad ^ ((r16 >> 1) & 3)) << 4;

  constexpr int TOT = (M_ / 256) * NTN;
  const int flat = blockIdx.x;
  const int jj = (flat & 7) * (TOT / 8) + (flat >> 3);
  const int nt = jj % NTN, mt = jj / NTN;
  const int n0 = nt * 256, m0 = mt * 256;

  const int srow = (wid << 4) + (lane >> 2);
  const int scol = ((lane & 3) ^ ((lane >> 3) & 3)) << 3;
  const unsigned short* gA0 = A  + (size_t)(m0 + srow) * K + scol;
  const unsigned short* gB0 = Bt + (size_t)(n0 + srow) * K + scol;
  const unsigned oA = (unsigned)wid * 1024u + (unsigned)lane * 16u;

  floatx4 acc[8][4] = {};
  bf16x8 af[4], bf[4];

  auto stageA = [&](int g) {
    unsigned short* d = (unsigned short*)(lds + (g & 3) * 32768 + oA);
    const unsigned short* s = gA0 + (size_t)g * 32;
    gl_lds16(s, d);
    gl_lds16(s + (size_t)128 * K, d + 4096);
  };
  auto stageB = [&](int g) {
    unsigned short* d = (unsigned short*)(lds + (g & 3) * 32768 + 16384 + oA);
    const unsigned short* s = gB0 + (size_t)g * 32;
    gl_lds16(s, d);
    gl_lds16(s + (size_t)128 * K, d + 4096);
  };

  auto phA = [&](int g, int gs, bool st) {
    const unsigned char* sl = lds + (g & 3) * 32768;
#pragma unroll
    for (int j = 0; j < 4; ++j)
      bf[j] = *(const bf16x8*)(sl + 16384 + (wn + j * 16 + r16) * 64 + csw);
#pragma unroll
    for (int i = 0; i < 4; ++i)
      af[i] = *(const bf16x8*)(sl + (wm + i * 16 + r16) * 64 + csw);
    if (st) stageA(gs);
    asm volatile("s_barrier" ::: "memory");
    asm volatile("s_waitcnt lgkmcnt(0)" ::: "memory");
    __builtin_amdgcn_sched_barrier(0);
    __builtin_amdgcn_s_setprio(1);
#pragma unroll
    for (int i = 0; i < 4; ++i)
#pragma unroll
      for (int j = 0; j < 4; ++j)
        acc[i][j] = __builtin_amdgcn_mfma_f32_16x16x32_bf16(af[i], bf[j], acc[i][j], 0, 0, 0);
    __builtin_amdgcn_s_setprio(0);
    asm volatile("s_barrier" ::: "memory");
  };
  auto phB = [&](int g, int gs, bool st) {
    const unsigned char* sl = lds + (g & 3) * 32768;
#pragma unroll
    for (int i = 0; i < 4; ++i)
      af[i] = *(const bf16x8*)(sl + (wm + (4 + i) * 16 + r16) * 64 + csw);
    if (st) stageB(gs);
    asm volatile("s_barrier" ::: "memory");
    asm volatile("s_waitcnt lgkmcnt(0)" ::: "memory");
    __builtin_amdgcn_sched_barrier(0);
    __builtin_amdgcn_s_setprio(1);
#pragma unroll
    for (int i = 0; i < 4; ++i)
#pragma unroll
      for (int j = 0; j < 4; ++j)
        acc[4 + i][j] = __builtin_amdgcn_mfma_f32_16x16x32_bf16(af[i], bf[j], acc[4 + i][j], 0, 0, 0);
    __builtin_amdgcn_s_setprio(0);
    // caller inserts vmcnt + barrier
  };

  stageA(0); stageB(0); stageA(1); stageB(1); stageA(2); stageB(2);
  asm volatile("s_waitcnt vmcnt(8)" ::: "memory");
  asm volatile("s_barrier" ::: "memory");

  for (int g = 0; g < NG - 3; ++g) {
    phA(g, g + 3, true);
    phB(g, g + 3, true);
    asm volatile("s_waitcnt vmcnt(8)" ::: "memory");
    asm volatile("s_barrier" ::: "memory");
  }
  phA(NG - 3, 0, false); phB(NG - 3, 0, false);
  asm volatile("s_waitcnt vmcnt(4)" ::: "memory");
  asm volatile("s_barrier" ::: "memory");
  phA(NG - 2, 0, false); phB(NG - 2, 0, false);
  asm volatile("s_waitcnt vmcnt(0)" ::: "memory");
  asm volatile("s_barrier" ::: "memory");
  phA(NG - 1, 0, false); phB(NG - 1, 0, false);
  asm volatile("s_barrier" ::: "memory");

  // ---- epilogue (conflict-free): 4 passes of 64 rows, fp32 stride 260 ----
  float* stg = (float*)smem;
  const bool isU = (MODE == 0) && (n0 < DHID);
  const int c4 = lane << 2;

  float4 bv = {}, sv = {};
  if (MODE == 0) {
    if (isU) { bv = *(const float4*)&bias0[n0 + c4]; sv = *(const float4*)&a_s[DHID + n0 + c4]; }
    else     { bv = *(const float4*)&bias1[(n0 - DHID) + c4]; }
  } else {
    bv = *(const float4*)&bias0[n0 + c4];
  }

  const int colS = tid & 255, ch = tid >> 8;
  float aa = 0.f, sbi = 0.f, ssc = 0.f;
  if (isU) { aa = a_s[n0 + colS]; sbi = bias0[n0 + colS]; ssc = a_s[DHID + n0 + colS]; }

#pragma unroll
  for (int p = 0; p < 4; ++p) {
    if ((wid >> 2) == (p >> 1)) {
      const int ib = (p & 1) * 4;
#pragma unroll
      for (int ii = 0; ii < 4; ++ii)
#pragma unroll
        for (int j = 0; j < 4; ++j) {
          const int col = (wid & 3) * 64 + j * 16 + r16;
#pragma unroll
          for (int r = 0; r < 4; ++r)
            stg[(ii * 16 + quad * 4 + r) * 260 + col] = acc[ib + ii][j][r];
        }
    }
    asm volatile("s_waitcnt lgkmcnt(0)" ::: "memory");
    asm volatile("s_barrier" ::: "memory");

    const int gmb = m0 + p * 64;
    if (isU) {
      float P = 0.f;
      const float* sp = &stg[(ch * 32) * 260 + colS];
#pragma unroll
      for (int r = 0; r < 32; ++r) { P = fmaf(aa, P, (sp[0] + sbi) * ssc); sp += 260; }
      const int gm0 = gmb + ch * 32;
      carry[((size_t)(gm0 >> 12) * NCH2 + ((gm0 & 4095) >> 5)) * DHID + n0 + colS] = P;
#pragma unroll
      for (int rr = 0; rr < 8; ++rr) {
        const int lr = (wid << 3) + rr;
        float4 v = *(const float4*)&stg[lr * 260 + c4];
        ushort4 o;
        o.x = f2bf((v.x + bv.x) * sv.x);
        o.y = f2bf((v.y + bv.y) * sv.y);
        o.z = f2bf((v.z + bv.z) * sv.z);
        o.w = f2bf((v.w + bv.w) * sv.w);
        *(ushort4*)&u_out[(size_t)(gmb + lr) * DHID + n0 + c4] = o;
      }
    } else if (MODE == 0) {
#pragma unroll
      for (int rr = 0; rr < 8; ++rr) {
        const int lr = (wid << 3) + rr;
        float4 v = *(const float4*)&stg[lr * 260 + c4];
        ushort4 o;
        o.x = f2bf(v.x + bv.x);
        o.y = f2bf(v.y + bv.y);
        o.z = f2bf(v.z + bv.z);
        o.w = f2bf(v.w + bv.w);
        *(ushort4*)&dx_buf[(size_t)(gmb + lr) * DOUT + (n0 - DHID) + c4] = o;
      }
    } else {
#pragma unroll
      for (int rr = 0; rr < 8; ++rr) {
        const int lr = (wid << 3) + rr;
        float4 v = *(const float4*)&stg[lr * 260 + c4];
        ushort4 dv = *(const ushort4*)&dx_in[(size_t)(gmb + lr) * DOUT + n0 + c4];
        float4 o;
        o.x = (v.x + bv.x + bf2f(dv.x)) * 0.5f;
        o.y = (v.y + bv.y + bf2f(dv.y)) * 0.5f;
        o.z = (v.z + bv.z + bf2f(dv.z)) * 0.5f;
        o.w = (v.w + bv.w + bf2f(dv.w)) * 0.5f;
        *(float4*)&out[(size_t)(gmb + lr) * DOUT + n0 + c4] = o;
      }
    }
    asm volatile("s_barrier" ::: "memory");
  }
}

// ---------- scan kernels ----------
__global__ __launch_bounds__(256) void scan_mid(const float* __restrict__ a_s,
                                                const float* __restrict__ h0,
                                                float* __restrict__ carry,
                                                float* __restrict__ h_last) {
  int idx = blockIdx.x * 256 + threadIdx.x;   // B_*DHID = 8192
  int d = idx & (DHID - 1);
  int b = idx >> 10;
  float a = a_s[d];
  float aL = a;
#pragma unroll
  for (int q = 0; q < 5; ++q) aL *= aL;       // a^32
  float st = h0[(size_t)b * DHID + d];
  float* p = &carry[(size_t)b * NCH2 * DHID + d];
  for (int cg = 0; cg < NCH2; cg += 8) {
    float loc[8];
#pragma unroll
    for (int j = 0; j < 8; ++j) loc[j] = p[(size_t)j * DHID];
#pragma unroll
    for (int j = 0; j < 8; ++j) {
      p[(size_t)j * DHID] = st;
      st = fmaf(aL, st, loc[j]);
    }
    p += (size_t)8 * DHID;
  }
  h_last[(size_t)b * DHID + d] = st;
}

__global__ __launch_bounds__(256) void scan2(unsigned short* __restrict__ u,
                                             const float* __restrict__ a_s,
                                             const float* __restrict__ carry) {
  int idx = blockIdx.x * 256 + threadIdx.x;
  int d8 = (idx & 127) * 8;
  int c  = (idx >> 7) & (NCH2 - 1);
  int b  = idx >> 14;
  float4 a0 = *(const float4*)&a_s[d8];
  float4 a1 = *(const float4*)&a_s[d8 + 4];
  const float* cp = &carry[((size_t)(b * NCH2 + c)) * DHID + d8];
  float4 e0 = *(const float4*)cp;
  float4 e1 = *(const float4*)(cp + 4);
  float h0_ = e0.x, h1 = e0.y, h2 = e0.z, h3 = e0.w;
  float h4 = e1.x, h5 = e1.y, h6 = e1.z, h7 = e1.w;
  unsigned short* up = u + ((size_t)(b * S_ + c * CH2)) * DHID + d8;
#pragma unroll 4
  for (int t = 0; t < CH2; ++t) {
    ushort4 q0 = *(const ushort4*)up;
    ushort4 q1 = *(const ushort4*)(up + 4);
    h0_ = fmaf(a0.x, h0_, bf2f(q0.x)); h1 = fmaf(a0.y, h1, bf2f(q0.y));
    h2  = fmaf(a0.z, h2,  bf2f(q0.z)); h3 = fmaf(a0.w, h3, bf2f(q0.w));
    h4  = fmaf(a1.x, h4,  bf2f(q1.x)); h5 = fmaf(a1.y, h5, bf2f(q1.y));
    h6  = fmaf(a1.z, h6,  bf2f(q1.z)); h7 = fmaf(a1.w, h7, bf2f(q1.w));
    ushort4 w0, w1;
    w0.x = f2bf(h0_); w0.y = f2bf(h1); w0.z = f2bf(h2); w0.w = f2bf(h3);
    w1.x = f2bf(h4);  w1.y = f2bf(h5); w1.z = f2bf(h6); w1.w = f2bf(h7);
    *(ushort4*)up = w0;
    *(ushort4*)(up + 4) = w1;
    up += DHID;
  }
}

extern "C" void kernel_launch(void* const* d_in, const int* in_sizes, int n_in,
                              void* d_out, int out_size, void* d_ws, size_t ws_size,
                              hipStream_t stream) {
  const float* x    = (const float*)d_in[0];
  const float* h0   = (const float*)d_in[1];
  const float* alog = (const float*)d_in[2];
  const float* Wdx  = (const float*)d_in[3];
  const float* bdx  = (const float*)d_in[4];
  const float* Win  = (const float*)d_in[5];
  const float* bin  = (const float*)d_in[6];
  const float* Wout = (const float*)d_in[7];
  const float* bout = (const float*)d_in[8];

  float* out    = (float*)d_out;
  float* h_last = out + (size_t)M_ * DOUT;

  char* ws = (char*)d_ws;
  unsigned short* xb    = (unsigned short*)(ws);                      // 32 MB
  unsigned short* ubuf  = (unsigned short*)(ws + 33554432ull);        // 64 MB (u -> h in-place)
  unsigned short* dxb   = (unsigned short*)(ws + 100663296ull);       // 32 MB
  unsigned short* wcat  = (unsigned short*)(ws + 134217728ull);       // 1.5 MB
  unsigned short* woutt = (unsigned short*)(ws + 135790592ull);       // 1 MB
  float*          a_s   = (float*)(ws + 136839168ull);                // 8 KB
  float*          carry = (float*)(ws + 136847360ull);                // 4 MB

  // 1 launch: all weight transposes + gate precompute + x->bf16
  prep_all<<<5124 + (M_ * DIN / 8) / 256, 256, 0, stream>>>(
      alog, Win, Wdx, Wout, x, a_s, wcat, woutt, xb);

  // GEMM1 (+fused chunk-local scan): coarse pipeline (measured best at K=512)
  gemm256c<DIN, 0, 6><<<dim3((M_ / 256) * 6), dim3(512), 0, stream>>>(
      xb, wcat, a_s, bin, bdx, ubuf, dxb, nullptr, nullptr, carry);

  // prefix over chunks + h_last
  scan_mid<<<(B_ * DHID) / 256, 256, 0, stream>>>(a_s, h0, carry, h_last);
  // full scan from exact entry states, u -> h in place
  scan2   <<<(B_ * NCH2 * (DHID / 8)) / 256, 256, 0, stream>>>(ubuf, a_s, carry);

  // GEMM2: fine-phased pipeline (measured best at K=1024)
  gemm256f<DHID, 1, 2><<<dim3((M_ / 256) * 2), dim3(512), 0, stream>>>(
      ubuf, woutt, a_s, bout, nullptr, nullptr, nullptr, dxb, out, nullptr);
}

// Round 5
// 272.403 us; speedup vs baseline: 1.0113x; 1.0113x over previous
//
#include <hip/hip_runtime.h>

// Problem constants (B,S,D_IN,D_HID,D_OUT) = (8,4096,512,1024,512)
#define B_    8
#define S_    4096
#define DIN   512
#define DHID  1024
#define DOUT  512
#define M_    (B_*S_)          // 32768
#define NCAT  (DHID + DOUT)    // 1536
#define CH2   32
#define NCH2  (S_/CH2)         // 128

typedef __bf16 bf16x8 __attribute__((ext_vector_type(8)));
typedef float  floatx4 __attribute__((ext_vector_type(4)));

__device__ __forceinline__ unsigned short f2bf(float f) {
  unsigned u = __builtin_bit_cast(unsigned, f);
  u = (u + 0x7FFFu + ((u >> 16) & 1u)) >> 16;   // RNE
  return (unsigned short)u;
}
__device__ __forceinline__ float bf2f(unsigned short h) {
  unsigned u = ((unsigned)h) << 16;
  return __builtin_bit_cast(float, u);
}

__device__ __forceinline__ void gl_lds16(const unsigned short* g, unsigned short* l) {
  __builtin_amdgcn_global_load_lds((const __attribute__((address_space(1))) void*)g,
                                   (__attribute__((address_space(3))) void*)l, 16, 0, 0);
}

// ---------- fused prep: wcat | woutt | a_s | x->bf16 (single launch) ----------
__global__ void prep_all(const float* __restrict__ logit,
                         const float* __restrict__ Win, const float* __restrict__ Wdx,
                         const float* __restrict__ Wout, const float* __restrict__ x,
                         float* __restrict__ a_s,
                         unsigned short* __restrict__ wcat,
                         unsigned short* __restrict__ woutt,
                         unsigned short* __restrict__ xb) {
  int bx = blockIdx.x;
  if (bx < 3072) {                       // Wcat^T: n in [0,1536), k in [0,512)
    int idx = bx * 256 + threadIdx.x;
    int n = idx >> 9, k = idx & 511;
    float v = (n < DHID) ? Win[(size_t)k * DHID + n] : Wdx[(size_t)k * DOUT + (n - DHID)];
    wcat[idx] = f2bf(v);
  } else if (bx < 5120) {                // Wout^T: n in [0,512), k in [0,1024)
    int idx = (bx - 3072) * 256 + threadIdx.x;
    int n = idx >> 10, k = idx & 1023;
    woutt[idx] = f2bf(Wout[(size_t)k * DOUT + n]);
  } else if (bx < 5124) {                // a_s
    int d = (bx - 5120) * 256 + threadIdx.x;
    if (d < DHID) {
      float a = 1.f / (1.f + expf(-logit[d]));
      a_s[d] = a;
      a_s[DHID + d] = sqrtf(fmaxf(1.f - a * a, 0.f));
    }
  } else {                               // x fp32 -> bf16, 8 elems/thread
    size_t i = (size_t)(bx - 5124) * 256 + threadIdx.x;
    const float4* p = (const float4*)x;
    float4 v0 = p[i * 2];
    float4 v1 = p[i * 2 + 1];
    uint4 o;
    o.x = (unsigned)f2bf(v0.x) | ((unsigned)f2bf(v0.y) << 16);
    o.y = (unsigned)f2bf(v0.z) | ((unsigned)f2bf(v0.w) << 16);
    o.z = (unsigned)f2bf(v1.x) | ((unsigned)f2bf(v1.y) << 16);
    o.w = (unsigned)f2bf(v1.z) | ((unsigned)f2bf(v1.w) << 16);
    *(uint4*)&xb[i * 8] = o;
  }
}

// ============ 256x256 coarse counted-vmcnt GEMM body (r3-proven, both GEMMs) =======
// Granule = 32-K slab, 4 LDS slots, prefetch distance 3, per granule:
// stage(t+3) -> 12 ds_read_b128 -> 32 MFMA -> vmcnt(8)+lgkmcnt(0) -> barrier.
// Swizzle: LDS linear for global_load_lds, source chunk pre-XOR'd, ds_read chunk
// ^= ((row>>1)&3) -> 2-way (free) bank access. Epilogue conflict-free (r2-proven).
// MODE 0: u=(c+b_in)*s bf16 + fused chunk-scan -> carry (cols NBASE..NBASE+256*NTN<1024)
// MODE 2: dx=c+b_dx bf16 (NBASE=1024)
// MODE 1: out=(c + b_out + dx)*0.5 fp32
template <int K, int MODE, int NTN, int NBASE>
__device__ __forceinline__ void gemm256_body(
    const unsigned short* __restrict__ A,
    const unsigned short* __restrict__ Bt,
    const float* __restrict__ a_s,
    const float* __restrict__ bias0,
    const float* __restrict__ bias1,
    unsigned short* __restrict__ u_out,
    unsigned short* __restrict__ dx_buf,
    const unsigned short* __restrict__ dx_in,
    float* __restrict__ out,
    float* __restrict__ carry)
{
  constexpr int NG = K / 32;             // granules
  __shared__ __align__(16) unsigned char smem[131072];
  unsigned char* lds = smem;

  const int tid  = threadIdx.x;
  const int lane = tid & 63, wid = tid >> 6;
  const int r16  = lane & 15, quad = lane >> 4;
  const int wm = (wid >> 2) * 128, wn = (wid & 3) * 64;
  const int csw = (quad ^ ((r16 >> 1) & 3)) << 4;   // read-side swizzled 16B chunk

  constexpr int TOT = (M_ / 256) * NTN;
  const int flat = blockIdx.x;
  const int jj = (flat & 7) * (TOT / 8) + (flat >> 3);
  const int nt = jj % NTN, mt = jj / NTN;
  const int n0 = NBASE + nt * 256, m0 = mt * 256;

  const int srow = (wid << 4) + (lane >> 2);                 // 0..127
  const int scol = ((lane & 3) ^ ((lane >> 3) & 3)) << 3;    // pre-swizzled src chunk
  const unsigned short* gA0 = A  + (size_t)(m0 + srow) * K + scol;
  const unsigned short* gB0 = Bt + (size_t)(n0 + srow) * K + scol;
  const unsigned oA = (unsigned)wid * 1024u + (unsigned)lane * 16u;  // linear LDS bytes

  floatx4 acc[8][4] = {};

  auto stage = [&](int slot, int g) {
    unsigned char* d = lds + slot * 32768;
    const unsigned short* sa = gA0 + (size_t)g * 32;
    const unsigned short* sb = gB0 + (size_t)g * 32;
    gl_lds16(sa, (unsigned short*)(d + oA));
    gl_lds16(sa + (size_t)128 * K, (unsigned short*)(d + oA + 8192));
    gl_lds16(sb, (unsigned short*)(d + 16384 + oA));
    gl_lds16(sb + (size_t)128 * K, (unsigned short*)(d + 16384 + oA + 8192));
  };

  auto compute = [&](int slot) {
    const unsigned char* pA = lds + slot * 32768;
    const unsigned char* pB = pA + 16384;
    bf16x8 af[8], bfr[4];
#pragma unroll
    for (int j = 0; j < 4; ++j)
      bfr[j] = *(const bf16x8*)(pB + (wn + j * 16 + r16) * 64 + csw);
#pragma unroll
    for (int i = 0; i < 8; ++i)
      af[i] = *(const bf16x8*)(pA + (wm + i * 16 + r16) * 64 + csw);
    __builtin_amdgcn_s_setprio(1);
#pragma unroll
    for (int i = 0; i < 8; ++i)
#pragma unroll
      for (int j = 0; j < 4; ++j)
        acc[i][j] = __builtin_amdgcn_mfma_f32_16x16x32_bf16(af[i], bfr[j], acc[i][j], 0, 0, 0);
    __builtin_amdgcn_s_setprio(0);
  };

  stage(0, 0); stage(1, 1); stage(2, 2);
  asm volatile("s_waitcnt vmcnt(8)" ::: "memory");
  __builtin_amdgcn_s_barrier();

  for (int t = 0; t < NG - 3; ++t) {
    stage((t + 3) & 3, t + 3);
    compute(t & 3);
    asm volatile("s_waitcnt vmcnt(8) lgkmcnt(0)" ::: "memory");
    __builtin_amdgcn_s_barrier();
  }
  compute((NG - 3) & 3);
  asm volatile("s_waitcnt vmcnt(4) lgkmcnt(0)" ::: "memory");
  __builtin_amdgcn_s_barrier();
  compute((NG - 2) & 3);
  asm volatile("s_waitcnt vmcnt(0) lgkmcnt(0)" ::: "memory");
  __builtin_amdgcn_s_barrier();
  compute((NG - 1) & 3);
  asm volatile("s_waitcnt lgkmcnt(0)" ::: "memory");
  __builtin_amdgcn_s_barrier();

  // ---- epilogue (conflict-free): 4 passes of 64 rows, fp32 stride 260 ----
  float* stg = (float*)smem;
  const int c4 = lane << 2;              // col base 0..252 (row-contiguous reads)

  float4 bv = {}, sv = {};
  if (MODE == 0) { bv = *(const float4*)&bias0[n0 + c4]; sv = *(const float4*)&a_s[DHID + n0 + c4]; }
  else if (MODE == 2) { bv = *(const float4*)&bias1[(n0 - DHID) + c4]; }
  else { bv = *(const float4*)&bias0[n0 + c4]; }

  // fused-scan mapping: 512 threads = 256 cols x 2 chunks of 32 rows (MODE 0 only)
  const int colS = tid & 255, ch = tid >> 8;
  float aa = 0.f, sbi = 0.f, ssc = 0.f;
  if (MODE == 0) { aa = a_s[n0 + colS]; sbi = bias0[n0 + colS]; ssc = a_s[DHID + n0 + colS]; }

#pragma unroll
  for (int p = 0; p < 4; ++p) {
    if ((wid >> 2) == (p >> 1)) {
      const int ib = (p & 1) * 4;
#pragma unroll
      for (int ii = 0; ii < 4; ++ii)
#pragma unroll
        for (int j = 0; j < 4; ++j) {
          const int col = (wid & 3) * 64 + j * 16 + r16;
#pragma unroll
          for (int r = 0; r < 4; ++r)
            stg[(ii * 16 + quad * 4 + r) * 260 + col] = acc[ib + ii][j][r];
        }
    }
    asm volatile("s_waitcnt lgkmcnt(0)" ::: "memory");
    __builtin_amdgcn_s_barrier();

    const int gmb = m0 + p * 64;
    if (MODE == 0) {
      // chunk-local weighted scan over 32 rows -> carry
      float P = 0.f;
      const float* sp = &stg[(ch * 32) * 260 + colS];
#pragma unroll
      for (int r = 0; r < 32; ++r) { P = fmaf(aa, P, (sp[0] + sbi) * ssc); sp += 260; }
      const int gm0 = gmb + ch * 32;
      carry[((size_t)(gm0 >> 12) * NCH2 + ((gm0 & 4095) >> 5)) * DHID + n0 + colS] = P;
      // u = (c + b_in) * s  (bf16), 8 rows per wave, row-contiguous LDS reads
#pragma unroll
      for (int rr = 0; rr < 8; ++rr) {
        const int lr = (wid << 3) + rr;
        float4 v = *(const float4*)&stg[lr * 260 + c4];
        ushort4 o;
        o.x = f2bf((v.x + bv.x) * sv.x);
        o.y = f2bf((v.y + bv.y) * sv.y);
        o.z = f2bf((v.z + bv.z) * sv.z);
        o.w = f2bf((v.w + bv.w) * sv.w);
        *(ushort4*)&u_out[(size_t)(gmb + lr) * DHID + n0 + c4] = o;
      }
    } else if (MODE == 2) {
#pragma unroll
      for (int rr = 0; rr < 8; ++rr) {
        const int lr = (wid << 3) + rr;
        float4 v = *(const float4*)&stg[lr * 260 + c4];
        ushort4 o;
        o.x = f2bf(v.x + bv.x);
        o.y = f2bf(v.y + bv.y);
        o.z = f2bf(v.z + bv.z);
        o.w = f2bf(v.w + bv.w);
        *(ushort4*)&dx_buf[(size_t)(gmb + lr) * DOUT + (n0 - DHID) + c4] = o;
      }
    } else {
#pragma unroll
      for (int rr = 0; rr < 8; ++rr) {
        const int lr = (wid << 3) + rr;
        float4 v = *(const float4*)&stg[lr * 260 + c4];
        ushort4 dv = *(const ushort4*)&dx_in[(size_t)(gmb + lr) * DOUT + n0 + c4];
        float4 o;
        o.x = (v.x + bv.x + bf2f(dv.x)) * 0.5f;
        o.y = (v.y + bv.y + bf2f(dv.y)) * 0.5f;
        o.z = (v.z + bv.z + bf2f(dv.z)) * 0.5f;
        o.w = (v.w + bv.w + bf2f(dv.w)) * 0.5f;
        *(float4*)&out[(size_t)(gmb + lr) * DOUT + n0 + c4] = o;
      }
    }
    __builtin_amdgcn_s_barrier();
  }
}

// Distinctly-named shells so rocprof attributes each GEMM separately.
__global__ __launch_bounds__(512, 2) void gemm_u(
    const unsigned short* __restrict__ A, const unsigned short* __restrict__ Bt,
    const float* __restrict__ a_s, const float* __restrict__ bin,
    unsigned short* __restrict__ u_out, float* __restrict__ carry) {
  gemm256_body<DIN, 0, 4, 0>(A, Bt, a_s, bin, nullptr, u_out, nullptr, nullptr, nullptr, carry);
}

__global__ __launch_bounds__(512, 2) void gemm_dx(
    const unsigned short* __restrict__ A, const unsigned short* __restrict__ Bt,
    const float* __restrict__ bdx, unsigned short* __restrict__ dx_buf) {
  gemm256_body<DIN, 2, 2, DHID>(A, Bt, nullptr, nullptr, bdx, nullptr, dx_buf, nullptr, nullptr, nullptr);
}

__global__ __launch_bounds__(512, 2) void gemm_out(
    const unsigned short* __restrict__ A, const unsigned short* __restrict__ Bt,
    const float* __restrict__ bout, const unsigned short* __restrict__ dx_in,
    float* __restrict__ out) {
  gemm256_body<DHID, 1, 2, 0>(A, Bt, nullptr, bout, nullptr, nullptr, nullptr, dx_in, out, nullptr);
}

// ---------- scan kernels ----------
__global__ __launch_bounds__(256) void scan_mid(const float* __restrict__ a_s,
                                                const float* __restrict__ h0,
                                                float* __restrict__ carry,
                                                float* __restrict__ h_last) {
  int idx = blockIdx.x * 256 + threadIdx.x;   // B_*DHID = 8192
  int d = idx & (DHID - 1);
  int b = idx >> 10;
  float a = a_s[d];
  float aL = a;
#pragma unroll
  for (int q = 0; q < 5; ++q) aL *= aL;       // a^32
  float st = h0[(size_t)b * DHID + d];
  float* p = &carry[(size_t)b * NCH2 * DHID + d];
  for (int cg = 0; cg < NCH2; cg += 8) {
    float loc[8];
#pragma unroll
    for (int j = 0; j < 8; ++j) loc[j] = p[(size_t)j * DHID];
#pragma unroll
    for (int j = 0; j < 8; ++j) {
      p[(size_t)j * DHID] = st;
      st = fmaf(aL, st, loc[j]);
    }
    p += (size_t)8 * DHID;
  }
  h_last[(size_t)b * DHID + d] = st;
}

__global__ __launch_bounds__(256) void scan2(unsigned short* __restrict__ u,
                                             const float* __restrict__ a_s,
                                             const float* __restrict__ carry) {
  int idx = blockIdx.x * 256 + threadIdx.x;
  int d8 = (idx & 127) * 8;
  int c  = (idx >> 7) & (NCH2 - 1);
  int b  = idx >> 14;
  float4 a0 = *(const float4*)&a_s[d8];
  float4 a1 = *(const float4*)&a_s[d8 + 4];
  const float* cp = &carry[((size_t)(b * NCH2 + c)) * DHID + d8];
  float4 e0 = *(const float4*)cp;
  float4 e1 = *(const float4*)(cp + 4);
  float h0_ = e0.x, h1 = e0.y, h2 = e0.z, h3 = e0.w;
  float h4 = e1.x, h5 = e1.y, h6 = e1.z, h7 = e1.w;
  unsigned short* up = u + ((size_t)(b * S_ + c * CH2)) * DHID + d8;
#pragma unroll 4
  for (int t = 0; t < CH2; ++t) {
    ushort4 q0 = *(const ushort4*)up;
    ushort4 q1 = *(const ushort4*)(up + 4);
    h0_ = fmaf(a0.x, h0_, bf2f(q0.x)); h1 = fmaf(a0.y, h1, bf2f(q0.y));
    h2  = fmaf(a0.z, h2,  bf2f(q0.z)); h3 = fmaf(a0.w, h3, bf2f(q0.w));
    h4  = fmaf(a1.x, h4,  bf2f(q1.x)); h5 = fmaf(a1.y, h5, bf2f(q1.y));
    h6  = fmaf(a1.z, h6,  bf2f(q1.z)); h7 = fmaf(a1.w, h7, bf2f(q1.w));
    ushort4 w0, w1;
    w0.x = f2bf(h0_); w0.y = f2bf(h1); w0.z = f2bf(h2); w0.w = f2bf(h3);
    w1.x = f2bf(h4);  w1.y = f2bf(h5); w1.z = f2bf(h6); w1.w = f2bf(h7);
    *(ushort4*)up = w0;
    *(ushort4*)(up + 4) = w1;
    up += DHID;
  }
}

extern "C" void kernel_launch(void* const* d_in, const int* in_sizes, int n_in,
                              void* d_out, int out_size, void* d_ws, size_t ws_size,
                              hipStream_t stream) {
  const float* x    = (const float*)d_in[0];
  const float* h0   = (const float*)d_in[1];
  const float* alog = (const float*)d_in[2];
  const float* Wdx  = (const float*)d_in[3];
  const float* bdx  = (const float*)d_in[4];
  const float* Win  = (const float*)d_in[5];
  const float* bin  = (const float*)d_in[6];
  const float* Wout = (const float*)d_in[7];
  const float* bout = (const float*)d_in[8];

  float* out    = (float*)d_out;
  float* h_last = out + (size_t)M_ * DOUT;

  char* ws = (char*)d_ws;
  unsigned short* xb    = (unsigned short*)(ws);                      // 32 MB
  unsigned short* ubuf  = (unsigned short*)(ws + 33554432ull);        // 64 MB (u -> h in-place)
  unsigned short* dxb   = (unsigned short*)(ws + 100663296ull);       // 32 MB
  unsigned short* wcat  = (unsigned short*)(ws + 134217728ull);       // 1.5 MB
  unsigned short* woutt = (unsigned short*)(ws + 135790592ull);       // 1 MB
  float*          a_s   = (float*)(ws + 136839168ull);                // 8 KB
  float*          carry = (float*)(ws + 136847360ull);                // 4 MB

  // 1 launch: all weight transposes + gate precompute + x->bf16
  prep_all<<<5124 + (M_ * DIN / 8) / 256, 256, 0, stream>>>(
      alog, Win, Wdx, Wout, x, a_s, wcat, woutt, xb);

  // GEMM1 u-panel (+fused chunk-local scan): coarse counted-vmcnt pipeline
  gemm_u<<<dim3((M_ / 256) * 4), dim3(512), 0, stream>>>(
      xb, wcat, a_s, bin, ubuf, carry);

  // prefix over chunks + h_last
  scan_mid<<<(B_ * DHID) / 256, 256, 0, stream>>>(a_s, h0, carry, h_last);
  // full scan from exact entry states, u -> h in place
  scan2   <<<(B_ * NCH2 * (DHID / 8)) / 256, 256, 0, stream>>>(ubuf, a_s, carry);

  // GEMM1 dx-panel (independent of the scan; fills the gap before GEMM2)
  gemm_dx<<<dim3((M_ / 256) * 2), dim3(512), 0, stream>>>(
      xb, wcat, bdx, dxb);

  // GEMM2: out = (dx + h@W_out + b_out)/2, coarse pipeline (r4 A/B: coarse > fine)
  gemm_out<<<dim3((M_ / 256) * 2), dim3(512), 0, stream>>>(
      ubuf, woutt, bout, dxb, out);
}

// Round 6
// 271.868 us; speedup vs baseline: 1.0133x; 1.0020x over previous
//
#include <hip/hip_runtime.h>

// Problem constants (B,S,D_IN,D_HID,D_OUT) = (8,4096,512,1024,512)
#define B_    8
#define S_    4096
#define DIN   512
#define DHID  1024
#define DOUT  512
#define M_    (B_*S_)          // 32768
#define NCAT  (DHID + DOUT)    // 1536
#define CH2   32
#define NCH2  (S_/CH2)         // 128

typedef __bf16 bf16x8 __attribute__((ext_vector_type(8)));
typedef float  floatx4 __attribute__((ext_vector_type(4)));

__device__ __forceinline__ unsigned short f2bf(float f) {
  unsigned u = __builtin_bit_cast(unsigned, f);
  u = (u + 0x7FFFu + ((u >> 16) & 1u)) >> 16;   // RNE
  return (unsigned short)u;
}
__device__ __forceinline__ float bf2f(unsigned short h) {
  unsigned u = ((unsigned)h) << 16;
  return __builtin_bit_cast(float, u);
}

__device__ __forceinline__ void gl_lds16(const unsigned short* g, unsigned short* l) {
  __builtin_amdgcn_global_load_lds((const __attribute__((address_space(1))) void*)g,
                                   (__attribute__((address_space(3))) void*)l, 16, 0, 0);
}

// ---------- fused prep: wcat | woutt | a_s | x->bf16 (single launch) ----------
__global__ void prep_all(const float* __restrict__ logit,
                         const float* __restrict__ Win, const float* __restrict__ Wdx,
                         const float* __restrict__ Wout, const float* __restrict__ x,
                         float* __restrict__ a_s,
                         unsigned short* __restrict__ wcat,
                         unsigned short* __restrict__ woutt,
                         unsigned short* __restrict__ xb) {
  int bx = blockIdx.x;
  if (bx < 3072) {                       // Wcat^T: n in [0,1536), k in [0,512)
    int idx = bx * 256 + threadIdx.x;
    int n = idx >> 9, k = idx & 511;
    float v = (n < DHID) ? Win[(size_t)k * DHID + n] : Wdx[(size_t)k * DOUT + (n - DHID)];
    wcat[idx] = f2bf(v);
  } else if (bx < 5120) {                // Wout^T: n in [0,512), k in [0,1024)
    int idx = (bx - 3072) * 256 + threadIdx.x;
    int n = idx >> 10, k = idx & 1023;
    woutt[idx] = f2bf(Wout[(size_t)k * DOUT + n]);
  } else if (bx < 5124) {                // a_s
    int d = (bx - 5120) * 256 + threadIdx.x;
    if (d < DHID) {
      float a = 1.f / (1.f + expf(-logit[d]));
      a_s[d] = a;
      a_s[DHID + d] = sqrtf(fmaxf(1.f - a * a, 0.f));
    }
  } else {                               // x fp32 -> bf16, 8 elems/thread
    size_t i = (size_t)(bx - 5124) * 256 + threadIdx.x;
    const float4* p = (const float4*)x;
    float4 v0 = p[i * 2];
    float4 v1 = p[i * 2 + 1];
    uint4 o;
    o.x = (unsigned)f2bf(v0.x) | ((unsigned)f2bf(v0.y) << 16);
    o.y = (unsigned)f2bf(v0.z) | ((unsigned)f2bf(v0.w) << 16);
    o.z = (unsigned)f2bf(v1.x) | ((unsigned)f2bf(v1.y) << 16);
    o.w = (unsigned)f2bf(v1.z) | ((unsigned)f2bf(v1.w) << 16);
    *(uint4*)&xb[i * 8] = o;
  }
}

// ================= COARSE 256x256 GEMM (r3-proven; merged GEMM1 + GEMM2) ===========
// Granule = 32-K slab, 4 LDS slots, prefetch distance 3, per granule:
// stage(t+3) -> 12 ds_read_b128 -> 32 MFMA -> vmcnt(8)+lgkmcnt(0) -> barrier.
// Swizzle: LDS linear for global_load_lds, source chunk pre-XOR'd, ds_read chunk
// ^= ((row>>1)&3) -> 2-way (free) bank access. Epilogue conflict-free (r2-proven).
template <int K, int MODE, int NTN>
__global__ __launch_bounds__(512, 2) void gemm256c(
    const unsigned short* __restrict__ A,
    const unsigned short* __restrict__ Bt,
    const float* __restrict__ a_s,
    const float* __restrict__ bias0,
    const float* __restrict__ bias1,
    unsigned short* __restrict__ u_out,
    unsigned short* __restrict__ dx_buf,
    const unsigned short* __restrict__ dx_in,
    float* __restrict__ out,
    float* __restrict__ carry)
{
  constexpr int NG = K / 32;             // granules
  __shared__ __align__(16) unsigned char smem[131072];
  unsigned char* lds = smem;

  const int tid  = threadIdx.x;
  const int lane = tid & 63, wid = tid >> 6;
  const int r16  = lane & 15, quad = lane >> 4;
  const int wm = (wid >> 2) * 128, wn = (wid & 3) * 64;
  const int csw = (quad ^ ((r16 >> 1) & 3)) << 4;   // read-side swizzled 16B chunk

  constexpr int TOT = (M_ / 256) * NTN;
  const int flat = blockIdx.x;
  const int jj = (flat & 7) * (TOT / 8) + (flat >> 3);
  const int nt = jj % NTN, mt = jj / NTN;
  const int n0 = nt * 256, m0 = mt * 256;

  const int srow = (wid << 4) + (lane >> 2);                 // 0..127
  const int scol = ((lane & 3) ^ ((lane >> 3) & 3)) << 3;    // pre-swizzled src chunk
  const unsigned short* gA0 = A  + (size_t)(m0 + srow) * K + scol;
  const unsigned short* gB0 = Bt + (size_t)(n0 + srow) * K + scol;
  const unsigned oA = (unsigned)wid * 1024u + (unsigned)lane * 16u;  // linear LDS bytes

  floatx4 acc[8][4] = {};

  auto stage = [&](int slot, int g) {
    unsigned char* d = lds + slot * 32768;
    const unsigned short* sa = gA0 + (size_t)g * 32;
    const unsigned short* sb = gB0 + (size_t)g * 32;
    gl_lds16(sa, (unsigned short*)(d + oA));
    gl_lds16(sa + (size_t)128 * K, (unsigned short*)(d + oA + 8192));
    gl_lds16(sb, (unsigned short*)(d + 16384 + oA));
    gl_lds16(sb + (size_t)128 * K, (unsigned short*)(d + 16384 + oA + 8192));
  };

  auto compute = [&](int slot) {
    const unsigned char* pA = lds + slot * 32768;
    const unsigned char* pB = pA + 16384;
    bf16x8 af[8], bfr[4];
#pragma unroll
    for (int j = 0; j < 4; ++j)
      bfr[j] = *(const bf16x8*)(pB + (wn + j * 16 + r16) * 64 + csw);
#pragma unroll
    for (int i = 0; i < 8; ++i)
      af[i] = *(const bf16x8*)(pA + (wm + i * 16 + r16) * 64 + csw);
    __builtin_amdgcn_s_setprio(1);
#pragma unroll
    for (int i = 0; i < 8; ++i)
#pragma unroll
      for (int j = 0; j < 4; ++j)
        acc[i][j] = __builtin_amdgcn_mfma_f32_16x16x32_bf16(af[i], bfr[j], acc[i][j], 0, 0, 0);
    __builtin_amdgcn_s_setprio(0);
  };

  stage(0, 0); stage(1, 1); stage(2, 2);
  asm volatile("s_waitcnt vmcnt(8)" ::: "memory");
  __builtin_amdgcn_s_barrier();

  for (int t = 0; t < NG - 3; ++t) {
    stage((t + 3) & 3, t + 3);
    compute(t & 3);
    asm volatile("s_waitcnt vmcnt(8) lgkmcnt(0)" ::: "memory");
    __builtin_amdgcn_s_barrier();
  }
  compute((NG - 3) & 3);
  asm volatile("s_waitcnt vmcnt(4) lgkmcnt(0)" ::: "memory");
  __builtin_amdgcn_s_barrier();
  compute((NG - 2) & 3);
  asm volatile("s_waitcnt vmcnt(0) lgkmcnt(0)" ::: "memory");
  __builtin_amdgcn_s_barrier();
  compute((NG - 1) & 3);
  asm volatile("s_waitcnt lgkmcnt(0)" ::: "memory");
  __builtin_amdgcn_s_barrier();

  // ---- epilogue (conflict-free): 4 passes of 64 rows, fp32 stride 260 ----
  float* stg = (float*)smem;
  const bool isU = (MODE == 0) && (n0 < DHID);
  const int c4 = lane << 2;

  float4 bv = {}, sv = {};
  if (MODE == 0) {
    if (isU) { bv = *(const float4*)&bias0[n0 + c4]; sv = *(const float4*)&a_s[DHID + n0 + c4]; }
    else     { bv = *(const float4*)&bias1[(n0 - DHID) + c4]; }
  } else {
    bv = *(const float4*)&bias0[n0 + c4];
  }

  const int colS = tid & 255, ch = tid >> 8;
  float aa = 0.f, sbi = 0.f, ssc = 0.f;
  if (isU) { aa = a_s[n0 + colS]; sbi = bias0[n0 + colS]; ssc = a_s[DHID + n0 + colS]; }

#pragma unroll
  for (int p = 0; p < 4; ++p) {
    if ((wid >> 2) == (p >> 1)) {
      const int ib = (p & 1) * 4;
#pragma unroll
      for (int ii = 0; ii < 4; ++ii)
#pragma unroll
        for (int j = 0; j < 4; ++j) {
          const int col = (wid & 3) * 64 + j * 16 + r16;
#pragma unroll
          for (int r = 0; r < 4; ++r)
            stg[(ii * 16 + quad * 4 + r) * 260 + col] = acc[ib + ii][j][r];
        }
    }
    asm volatile("s_waitcnt lgkmcnt(0)" ::: "memory");
    __builtin_amdgcn_s_barrier();

    const int gmb = m0 + p * 64;
    if (isU) {
      float P = 0.f;
      const float* sp = &stg[(ch * 32) * 260 + colS];
#pragma unroll
      for (int r = 0; r < 32; ++r) { P = fmaf(aa, P, (sp[0] + sbi) * ssc); sp += 260; }
      const int gm0 = gmb + ch * 32;
      carry[((size_t)(gm0 >> 12) * NCH2 + ((gm0 & 4095) >> 5)) * DHID + n0 + colS] = P;
#pragma unroll
      for (int rr = 0; rr < 8; ++rr) {
        const int lr = (wid << 3) + rr;
        float4 v = *(const float4*)&stg[lr * 260 + c4];
        ushort4 o;
        o.x = f2bf((v.x + bv.x) * sv.x);
        o.y = f2bf((v.y + bv.y) * sv.y);
        o.z = f2bf((v.z + bv.z) * sv.z);
        o.w = f2bf((v.w + bv.w) * sv.w);
        *(ushort4*)&u_out[(size_t)(gmb + lr) * DHID + n0 + c4] = o;
      }
    } else if (MODE == 0) {
#pragma unroll
      for (int rr = 0; rr < 8; ++rr) {
        const int lr = (wid << 3) + rr;
        float4 v = *(const float4*)&stg[lr * 260 + c4];
        ushort4 o;
        o.x = f2bf(v.x + bv.x);
        o.y = f2bf(v.y + bv.y);
        o.z = f2bf(v.z + bv.z);
        o.w = f2bf(v.w + bv.w);
        *(ushort4*)&dx_buf[(size_t)(gmb + lr) * DOUT + (n0 - DHID) + c4] = o;
      }
    } else {
#pragma unroll
      for (int rr = 0; rr < 8; ++rr) {
        const int lr = (wid << 3) + rr;
        float4 v = *(const float4*)&stg[lr * 260 + c4];
        ushort4 dv = *(const ushort4*)&dx_in[(size_t)(gmb + lr) * DOUT + n0 + c4];
        float4 o;
        o.x = (v.x + bv.x + bf2f(dv.x)) * 0.5f;
        o.y = (v.y + bv.y + bf2f(dv.y)) * 0.5f;
        o.z = (v.z + bv.z + bf2f(dv.z)) * 0.5f;
        o.w = (v.w + bv.w + bf2f(dv.w)) * 0.5f;
        *(float4*)&out[(size_t)(gmb + lr) * DOUT + n0 + c4] = o;
      }
    }
    __builtin_amdgcn_s_barrier();
  }
}

// ---------- scan kernels ----------
__global__ __launch_bounds__(256) void scan_mid(const float* __restrict__ a_s,
                                                const float* __restrict__ h0,
                                                float* __restrict__ carry,
                                                float* __restrict__ h_last) {
  int idx = blockIdx.x * 256 + threadIdx.x;   // B_*DHID = 8192
  int d = idx & (DHID - 1);
  int b = idx >> 10;
  float a = a_s[d];
  float aL = a;
#pragma unroll
  for (int q = 0; q < 5; ++q) aL *= aL;       // a^32
  float st = h0[(size_t)b * DHID + d];
  float* p = &carry[(size_t)b * NCH2 * DHID + d];
  for (int cg = 0; cg < NCH2; cg += 8) {
    float loc[8];
#pragma unroll
    for (int j = 0; j < 8; ++j) loc[j] = p[(size_t)j * DHID];
#pragma unroll
    for (int j = 0; j < 8; ++j) {
      p[(size_t)j * DHID] = st;
      st = fmaf(aL, st, loc[j]);
    }
    p += (size_t)8 * DHID;
  }
  h_last[(size_t)b * DHID + d] = st;
}

// 4 hidden-dims per thread (vs 8): 262144 threads -> 1024 blocks, 4 waves/SIMD,
// doubles TLP for the 32-step serial fma chain (was thread-count-limited at 2/SIMD).
__global__ __launch_bounds__(256) void scan2(unsigned short* __restrict__ u,
                                             const float* __restrict__ a_s,
                                             const float* __restrict__ carry) {
  int idx = blockIdx.x * 256 + threadIdx.x;   // 262144
  int d4 = (idx & 255) * 4;
  int c  = (idx >> 8) & (NCH2 - 1);
  int b  = idx >> 15;
  float4 a0 = *(const float4*)&a_s[d4];
  const float* cp = &carry[((size_t)(b * NCH2 + c)) * DHID + d4];
  float4 e0 = *(const float4*)cp;
  float h0_ = e0.x, h1 = e0.y, h2 = e0.z, h3 = e0.w;
  unsigned short* up = u + ((size_t)(b * S_ + c * CH2)) * DHID + d4;
#pragma unroll 4
  for (int t = 0; t < CH2; ++t) {
    ushort4 q0 = *(const ushort4*)up;
    h0_ = fmaf(a0.x, h0_, bf2f(q0.x)); h1 = fmaf(a0.y, h1, bf2f(q0.y));
    h2  = fmaf(a0.z, h2,  bf2f(q0.z)); h3 = fmaf(a0.w, h3, bf2f(q0.w));
    ushort4 w0;
    w0.x = f2bf(h0_); w0.y = f2bf(h1); w0.z = f2bf(h2); w0.w = f2bf(h3);
    *(ushort4*)up = w0;
    up += DHID;
  }
}

extern "C" void kernel_launch(void* const* d_in, const int* in_sizes, int n_in,
                              void* d_out, int out_size, void* d_ws, size_t ws_size,
                              hipStream_t stream) {
  const float* x    = (const float*)d_in[0];
  const float* h0   = (const float*)d_in[1];
  const float* alog = (const float*)d_in[2];
  const float* Wdx  = (const float*)d_in[3];
  const float* bdx  = (const float*)d_in[4];
  const float* Win  = (const float*)d_in[5];
  const float* bin  = (const float*)d_in[6];
  const float* Wout = (const float*)d_in[7];
  const float* bout = (const float*)d_in[8];

  float* out    = (float*)d_out;
  float* h_last = out + (size_t)M_ * DOUT;

  char* ws = (char*)d_ws;
  unsigned short* xb    = (unsigned short*)(ws);                      // 32 MB
  unsigned short* ubuf  = (unsigned short*)(ws + 33554432ull);        // 64 MB (u -> h in-place)
  unsigned short* dxb   = (unsigned short*)(ws + 100663296ull);       // 32 MB
  unsigned short* wcat  = (unsigned short*)(ws + 134217728ull);       // 1.5 MB
  unsigned short* woutt = (unsigned short*)(ws + 135790592ull);       // 1 MB
  float*          a_s   = (float*)(ws + 136839168ull);                // 8 KB
  float*          carry = (float*)(ws + 136847360ull);                // 4 MB

  // 1 launch: all weight transposes + gate precompute + x->bf16
  prep_all<<<5124 + (M_ * DIN / 8) / 256, 256, 0, stream>>>(
      alog, Win, Wdx, Wout, x, a_s, wcat, woutt, xb);

  // GEMM1 merged (+fused chunk-local scan): coarse counted-vmcnt pipeline (r3-proven)
  gemm256c<DIN, 0, 6><<<dim3((M_ / 256) * 6), dim3(512), 0, stream>>>(
      xb, wcat, a_s, bin, bdx, ubuf, dxb, nullptr, nullptr, carry);

  // prefix over chunks + h_last
  scan_mid<<<(B_ * DHID) / 256, 256, 0, stream>>>(a_s, h0, carry, h_last);
  // full scan from exact entry states, u -> h in place (d4, 2x TLP)
  scan2   <<<(B_ * NCH2 * (DHID / 4)) / 256, 256, 0, stream>>>(ubuf, a_s, carry);

  // GEMM2: out = (dx + h@W_out + b_out)/2, coarse pipeline (r4 A/B: coarse > fine)
  gemm256c<DHID, 1, 2><<<dim3((M_ / 256) * 2), dim3(512), 0, stream>>>(
      ubuf, woutt, nullptr, bout, nullptr, nullptr, nullptr, dxb, out, nullptr);
}